// Round 15
// baseline (112.290 us; speedup 1.0000x reference)
//
#include <hip/hip_runtime.h>
#include <hip/hip_fp16.h>
#include <stdint.h>

// x[16384,2048] f32, w[2048,2048] f32, bias[2048] f32, scalar scales.
// M=16384, N=2048, K=2048. Output f16 values stored as f32.
#define MDIM 16384
#define NDIM 2048
#define KDIM 2048

typedef __attribute__((ext_vector_type(4))) float f32x4;
typedef __attribute__((ext_vector_type(4))) int   i32x4;
typedef __attribute__((ext_vector_type(8))) int   i32x8;

#if defined(__has_builtin)
#if __has_builtin(__builtin_amdgcn_cvt_pk_fp8_f32)
#define HAVE_CVT_PK_FP8 1
#endif
#endif

// ---------------------------------------------------------------------------
// f32 -> e4m3fn (OCP), RTNE, saturating (== clip(+-448) then cast).
// ---------------------------------------------------------------------------
__device__ __forceinline__ unsigned f32_to_e4m3(float x) {
    float q = fminf(448.f, fmaxf(-448.f, x));
    unsigned ub = __float_as_uint(q);
    unsigned sgn = (ub >> 24) & 0x80u;
    float aq = fabsf(q);
    int E = (int)((__float_as_uint(aq) >> 23) & 0xff) - 127;
    if (E < -6) E = -6;
    float rq = __uint_as_float((unsigned)(130 - E) << 23);  // 2^(3-E), exact
    int m = (int)rintf(aq * rq);                            // RTNE, exact scale
    if (m == 16) { m = 8; E += 1; }
    unsigned bits;
    if (m < 8) bits = sgn | (unsigned)m;
    else       bits = sgn | ((unsigned)(E + 7) << 3) | (unsigned)(m - 8);
    return bits;
}

__device__ __forceinline__ uint32_t pack4_e4m3(float a, float b, float c, float d) {
#ifdef HAVE_CVT_PK_FP8
    int r = __builtin_amdgcn_cvt_pk_fp8_f32(a, b, 0, false);   // bytes 0-1
    r = __builtin_amdgcn_cvt_pk_fp8_f32(c, d, r, true);        // bytes 2-3
    return (uint32_t)r;
#else
    return f32_to_e4m3(a) | (f32_to_e4m3(b) << 8) |
           (f32_to_e4m3(c) << 16) | (f32_to_e4m3(d) << 24);
#endif
}

// x-quant: linear layout.  w-quant: fragment-major packed layout Bp
// (verified r8-r14): 2048B block (n16 = col>>4, kb = ktile) holds at
// lane*32 (lane = g*16 + r15) bytes w[n16*16+r15][kb*128 + g*32 .. +31].
__global__ void quant_both_kernel(const float* __restrict__ x,
                                  uint8_t* __restrict__ xq,
                                  const float* __restrict__ w,
                                  uint8_t* __restrict__ wq,
                                  const float* __restrict__ s_in,
                                  const float* __restrict__ s_w) {
    if (blockIdx.x < 2048) {
        float sc = s_in[0];
        unsigned n16 = (unsigned)((size_t)MDIM * KDIM / 16);
        unsigned i = blockIdx.x * 256 + threadIdx.x;
        for (; i < n16; i += 2048 * 256) {
            const float4* xp = (const float4*)(x + (size_t)i * 16);
            uint32_t wd[4];
#pragma unroll
            for (int j = 0; j < 4; ++j) {
                float4 v = xp[j];
                wd[j] = pack4_e4m3(v.x / sc, v.y / sc, v.z / sc, v.w / sc);
            }
            ((uint4*)xq)[i] = make_uint4(wd[0], wd[1], wd[2], wd[3]);
        }
    } else {
        float sc = s_w[0];
        unsigned n16 = (unsigned)((size_t)NDIM * KDIM / 16);
        unsigned i = (blockIdx.x - 2048) * 256 + threadIdx.x;
        for (; i < n16; i += 256 * 256) {
            const float4* xp = (const float4*)(w + (size_t)i * 16);
            uint32_t wd[4];
#pragma unroll
            for (int j = 0; j < 4; ++j) {
                float4 v = xp[j];
                wd[j] = pack4_e4m3(v.x / sc, v.y / sc, v.z / sc, v.w / sc);
            }
            unsigned r = i >> 7, kc = i & 127;
            unsigned idx = ((r >> 4) * 16 + (kc >> 3)) * 128 +
                           ((kc & 7) >> 1) * 32 + (r & 15) * 2 + (kc & 1);
            ((uint4*)wq)[idx] = make_uint4(wd[0], wd[1], wd[2], wd[3]);
        }
    }
}

// ---------------------------------------------------------------------------
// GEMM: C = Aq * Bp^T, fp8 e4m3, mfma_scale_f32_16x16x128_f8f6f4 (unit
// scales: exact, 2x fp8 rate; verified r4-r14).
//
// Round-15: PORT BALANCING.  Conserved operand traffic = 192KB/CU-tile
// (8 waves x 24KB incl duplication).  r13 put 192KB on LDS (~2000cy, bound);
// r14 put 128KB on L2 (~2180cy at the 60B/cy/CU measured ceiling, bound).
// Split per wave: af 4 frags LDS + bf = 6 frags L2-direct + 2 frags LDS:
//   LDS/CU-tile = (af reads 32K + A-DMA 16K + bf67 reads 16K + Bp-DMA 8K) x2
//               ~ 104KB ~ 1150cy (52% of MFMA 2208cy)
//   L2/CU-tile  = 12KB x 4 waves x 2 blocks = 96KB ~ 1710cy (77%)
// Both sub-critical for the first time.  Block 128x256, 4 waves 2Mx2N,
// per-wave 64x128, 2 blocks/CU (launch_bounds(256,2)); regs unchanged
// from r14 (bf 12-load persistent + 2 LDS-read; VGPR ~124 + acc 128).
//
// Per tile t: {STAGE_A(t+1) 4 DMA + STAGE_BP(t+1) 2 DMA; fence;
//   bf67 ds_read; af-rolling 4x[ds_read pair + MFMA8];
//   LOAD_BF05(t+1) 12 loads; vmcnt(12) [drains the 6 DMA, FIFO-audited];
//   barrier}.  Entry invariant: bf05(t) 12 in flight, A(t)/Bp(t) in LDS.
// A chunk swizzle per 128B row: phys=(c+row)&7 (2-way residual, r4-r14).
// Bp-in-LDS: linear frag blocks [wc0n6][wc0n7][wc1n6][wc1n7] x 2KB; lane
// reads lane*32 (4-way conflict, 4 reads/wave-tile only - accepted).
// LDS: A dbuf 2x16K @0 | Bp dbuf 2x8K @32768 | epilogue slab 32K @0.
// Epilogue: [32][256] f32 slab, 4 passes, 1KiB dwordx4 rows.
// ---------------------------------------------------------------------------
#define BM 128
#define BN 256
#define BKB 128
#define NKT (KDIM / BKB)   // 16

__device__ __forceinline__ void gload_lds16(const uint8_t* g, uint8_t* l) {
    __builtin_amdgcn_global_load_lds(
        (const __attribute__((address_space(1))) void*)g,
        (__attribute__((address_space(3))) void*)l, 16, 0, 0);
}

__device__ __forceinline__ void barrier_raw() {
    asm volatile("" ::: "memory");
    __builtin_amdgcn_s_barrier();
    asm volatile("" ::: "memory");
}

__global__ __launch_bounds__(256, 2) void gemm_fp8_kernel(
    const uint8_t* __restrict__ Aq, const uint8_t* __restrict__ Bp,
    const float* __restrict__ bias, const float* __restrict__ s_in,
    const float* __restrict__ s_w, float* __restrict__ out) {

    extern __shared__ uint8_t lds[];   // 49152 B: A 2x16K @0, Bp 2x8K @32768

    // XCD-aware bijective swizzle (nwg = 1024, divisible by 8)
    int nwg = gridDim.x;
    int cpx = nwg >> 3;
    int bid = blockIdx.x;
    int swz = (bid & 7) * cpx + (bid >> 3);
    int tm = swz >> 3;                 // tiles_n = 8
    int tn = swz & 7;
    int row0 = tm * BM;
    int col0 = tn * BN;

    int tid  = threadIdx.x;
    int lane = tid & 63;
    int wid  = tid >> 6;               // 4 waves
    int wr = wid >> 1, wc = wid & 1;   // 2M x 2N, per-wave 64x128
    int r15 = lane & 15;
    int g   = lane >> 4;

    int perm0 = ((2 * g + r15) & 7) << 4;
    int perm1 = ((2 * g + 1 + r15) & 7) << 4;

    // ---- A staging: 1024 chunks/tile (128 rows x 8), 4 per thread ----
    int ssrc[4], sdst[4];
#pragma unroll
    for (int i = 0; i < 4; ++i) {
        int p = i * 256 + tid;
        int lrow = p >> 3;
        int c = ((p & 7) - (lrow & 7)) & 7;
        ssrc[i] = lrow * KDIM + c * 16;
        sdst[i] = p * 16;
    }
    const uint8_t* Asrc = Aq + (size_t)row0 * KDIM;

#define STAGE_A(KT, BUF)                                                      \
    {                                                                         \
        _Pragma("unroll")                                                     \
        for (int j_ = 0; j_ < 4; ++j_)                                        \
            gload_lds16(Asrc + ssrc[j_] + (size_t)(KT) * BKB, (BUF) + sdst[j_]); \
    }

    // ---- Bp partial staging: frags {wc,n6},{wc,n7} both wc = 8KB/tile,
    //      512 chunks, 2 per thread ----
    size_t bpsrc[2]; int bpdst[2];
#pragma unroll
    for (int j = 0; j < 2; ++j) {
        int cj = j * 256 + tid;
        int fj = cj >> 7;                          // 0..3
        int gfj = tn * 16 + (fj >> 1) * 8 + 6 + (fj & 1);
        bpsrc[j] = (size_t)gfj * 32768 + (cj & 127) * 16;
        bpdst[j] = cj * 16;
    }

#define STAGE_BP(KT, BO)                                                      \
    {                                                                         \
        _Pragma("unroll")                                                     \
        for (int j_ = 0; j_ < 2; ++j_)                                        \
            gload_lds16(Bp + bpsrc[j_] + (size_t)(KT) * 2048,                 \
                        &lds[32768 + (BO)] + bpdst[j_]);                      \
    }

    // ---- B fragment base (packed layout; r8-r14-verified), frags 0..5 ----
    const uint8_t* Bbase = Bp + (size_t)(tn * 16 + wc * 8) * 32768 + lane * 32;

#define LOAD_BF1(DST, N, KT)                                                  \
    {                                                                         \
        const uint8_t* p_ = Bbase + (size_t)(N) * 32768 + (size_t)(KT) * 2048; \
        i32x4 lo = *(const i32x4*)p_;                                         \
        i32x4 hi = *(const i32x4*)(p_ + 16);                                  \
        _Pragma("unroll")                                                     \
        for (int q_ = 0; q_ < 4; ++q_) { DST[q_] = lo[q_]; DST[4 + q_] = hi[q_]; } \
    }

#define LOAD_BF05(KT)                                                         \
    LOAD_BF1(bf0, 0, KT); LOAD_BF1(bf1, 1, KT); LOAD_BF1(bf2, 2, KT);         \
    LOAD_BF1(bf3, 3, KT); LOAD_BF1(bf4, 4, KT); LOAD_BF1(bf5, 5, KT);

    // bf6/bf7 from LDS (cur Bp buf half at byte offset BOB)
#define LOAD_BF67(BOB)                                                        \
    {                                                                         \
        const uint8_t* p6_ = lds + 32768 + (BOB) + (wc * 2 + 0) * 2048 + lane * 32; \
        const uint8_t* p7_ = lds + 32768 + (BOB) + (wc * 2 + 1) * 2048 + lane * 32; \
        i32x4 lo6 = *(const i32x4*)p6_; i32x4 hi6 = *(const i32x4*)(p6_ + 16); \
        i32x4 lo7 = *(const i32x4*)p7_; i32x4 hi7 = *(const i32x4*)(p7_ + 16); \
        _Pragma("unroll")                                                     \
        for (int q_ = 0; q_ < 4; ++q_) {                                      \
            bf6[q_] = lo6[q_]; bf6[4 + q_] = hi6[q_];                         \
            bf7[q_] = lo7[q_]; bf7[4 + q_] = hi7[q_];                         \
        }                                                                     \
    }

    int aRow0 = wr * 64 + r15;         // + m*16

#define LOAD_AF1(DST, bo, M)                                                  \
    {                                                                         \
        const uint8_t* rp = lds + (bo) + (aRow0 + (M) * 16) * 128;            \
        i32x4 lo = *(const i32x4*)(rp + perm0);                               \
        i32x4 hi = *(const i32x4*)(rp + perm1);                               \
        _Pragma("unroll")                                                     \
        for (int q_ = 0; q_ < 4; ++q_) { DST[q_] = lo[q_]; DST[4 + q_] = hi[q_]; } \
    }

#define MFMA8(AF, M)                                                          \
    __builtin_amdgcn_s_setprio(1);                                            \
    acc[M][0] = __builtin_amdgcn_mfma_scale_f32_16x16x128_f8f6f4(             \
        AF, bf0, acc[M][0], 0, 0, 0, 127, 0, 127);                            \
    acc[M][1] = __builtin_amdgcn_mfma_scale_f32_16x16x128_f8f6f4(             \
        AF, bf1, acc[M][1], 0, 0, 0, 127, 0, 127);                            \
    acc[M][2] = __builtin_amdgcn_mfma_scale_f32_16x16x128_f8f6f4(             \
        AF, bf2, acc[M][2], 0, 0, 0, 127, 0, 127);                            \
    acc[M][3] = __builtin_amdgcn_mfma_scale_f32_16x16x128_f8f6f4(             \
        AF, bf3, acc[M][3], 0, 0, 0, 127, 0, 127);                            \
    acc[M][4] = __builtin_amdgcn_mfma_scale_f32_16x16x128_f8f6f4(             \
        AF, bf4, acc[M][4], 0, 0, 0, 127, 0, 127);                            \
    acc[M][5] = __builtin_amdgcn_mfma_scale_f32_16x16x128_f8f6f4(             \
        AF, bf5, acc[M][5], 0, 0, 0, 127, 0, 127);                            \
    acc[M][6] = __builtin_amdgcn_mfma_scale_f32_16x16x128_f8f6f4(             \
        AF, bf6, acc[M][6], 0, 0, 0, 127, 0, 127);                            \
    acc[M][7] = __builtin_amdgcn_mfma_scale_f32_16x16x128_f8f6f4(             \
        AF, bf7, acc[M][7], 0, 0, 0, 127, 0, 127);                            \
    __builtin_amdgcn_s_setprio(0);

    f32x4 acc[4][8];
#pragma unroll
    for (int m = 0; m < 4; ++m)
#pragma unroll
        for (int n = 0; n < 8; ++n)
            acc[m][n] = (f32x4){0.f, 0.f, 0.f, 0.f};

    i32x8 bf0, bf1, bf2, bf3, bf4, bf5, bf6, bf7;

    uint8_t* buf0 = &lds[0];
    uint8_t* buf1 = &lds[16384];

    // ---- prologue: A(0) 4 DMA + Bp(0) 2 DMA; bf05(0) 12 loads;
    //      vmcnt(12) drains DMA, leaves bf05(0) in flight; barrier ----
    STAGE_A(0, buf0);
    STAGE_BP(0, 0u);
    asm volatile("" ::: "memory");     // pin DMA before bf in VMEM FIFO
    LOAD_BF05(0);
    asm volatile("s_waitcnt vmcnt(12)" ::: "memory");
    barrier_raw();

    // Entry invariant tile T: bf05(T) 12 in flight (oldest); A(T),Bp(T) in LDS.
#define TILE_BODY(T)                                                          \
    {                                                                         \
        const unsigned bo  = ((unsigned)(T) & 1) << 14;                       \
        const unsigned bob = ((unsigned)(T) & 1) << 13;                       \
        if ((T) + 1 < NKT) {                                                  \
            STAGE_A((T) + 1, (((T) & 1) ? buf0 : buf1));                      \
            STAGE_BP((T) + 1, (((T) & 1) ? 0u : 8192u));                      \
        }                                                                     \
        asm volatile("" ::: "memory");                                        \
        LOAD_BF67(bob);                                                       \
        i32x8 afE, afO;                                                       \
        LOAD_AF1(afE, bo, 0);   /* compiler: counted vmcnt for bf05(T) */     \
        LOAD_AF1(afO, bo, 1); MFMA8(afE, 0);                                  \
        LOAD_AF1(afE, bo, 2); MFMA8(afO, 1);                                  \
        LOAD_AF1(afO, bo, 3); MFMA8(afE, 2);                                  \
                              MFMA8(afO, 3);                                  \
        if ((T) + 1 < NKT) {                                                  \
            LOAD_BF05((T) + 1);            /* 12 loads, reuse bf regs */      \
            asm volatile("s_waitcnt vmcnt(12)" ::: "memory"); /* DMA in */    \
        } else {                                                              \
            asm volatile("s_waitcnt vmcnt(0)" ::: "memory");                  \
        }                                                                     \
        barrier_raw();                                                        \
    }

    for (int t = 0; t < NKT; ++t)
        TILE_BODY(t);

    // ---- epilogue: f16 double-round + bias; [32][256] f32 slab, 4 passes --
    float s = s_in[0] * s_w[0];
    float* slab = (float*)lds;
    __half hb[8];
#pragma unroll
    for (int n = 0; n < 8; ++n)
        hb[n] = __float2half(bias[col0 + wc * 128 + n * 16 + r15]);

#pragma unroll
    for (int q = 0; q < 4; ++q) {            // out rows [q*32, q*32+32)
        if (wr == (q >> 1)) {
            const int mbase = 2 * (q & 1);
#pragma unroll
            for (int n = 0; n < 8; ++n) {
                int colb = wc * 128 + n * 16 + r15;
#pragma unroll
                for (int mm = 0; mm < 2; ++mm) {
                    int sr = mm * 16 + g * 4;
#pragma unroll
                    for (int r = 0; r < 4; ++r) {
                        __half h = __float2half(acc[mbase + mm][n][r] * s);
                        slab[(sr + r) * 256 + colb] = __half2float(__hadd(h, hb[n]));
                    }
                }
            }
        }
        barrier_raw();
        // 32 rows x 1KiB; each wave 8 rows (64 lanes x 16B per row)
#pragma unroll
        for (int it = 0; it < 8; ++it) {
            int srow = wid * 8 + it;
            f32x4 vv = *(const f32x4*)&slab[srow * 256 + lane * 4];
            int grow = row0 + q * 32 + srow;
            *(f32x4*)&out[(size_t)grow * NDIM + col0 + lane * 4] = vv;
        }
        barrier_raw();
    }
#undef STAGE_A
#undef STAGE_BP
#undef LOAD_BF1
#undef LOAD_BF05
#undef LOAD_BF67
#undef LOAD_AF1
#undef MFMA8
#undef TILE_BODY
}

// ---------------------------------------------------------------------------
extern "C" void kernel_launch(void* const* d_in, const int* in_sizes, int n_in,
                              void* d_out, int out_size, void* d_ws, size_t ws_size,
                              hipStream_t stream) {
    const float* x      = (const float*)d_in[0];   // [16384, 2048]
    const float* weight = (const float*)d_in[1];   // [2048, 2048]
    const float* bias   = (const float*)d_in[2];   // [2048]
    const float* s_in   = (const float*)d_in[3];   // [1]
    const float* s_w    = (const float*)d_in[4];   // [1]
    float* out          = (float*)d_out;

    uint8_t* xq = (uint8_t*)d_ws;                          // 33.5 MB (linear)
    uint8_t* wq = (uint8_t*)d_ws + (size_t)MDIM * KDIM;    // 4.2 MB (packed)

    quant_both_kernel<<<2304, 256, 0, stream>>>(x, xq, weight, wq, s_in, s_w);

    dim3 grid((MDIM / BM) * (NDIM / BN));   // 128 * 8 = 1024
    gemm_fp8_kernel<<<grid, 256, 49152, stream>>>(xq, wq, bias, s_in, s_w, out);
}